// Round 10
// baseline (62.671 us; speedup 1.0000x reference)
//
#include <hip/hip_runtime.h>
#include <hip/hip_bf16.h>

typedef unsigned short u16;
typedef unsigned int u32;
typedef unsigned long long u64;

#define THREADS 256
constexpr int CH = 64;        // in/out channels
constexpr int PP = 32;        // neighbors per point
constexpr int TM = 16;        // points per block

// ---- LDS layout (bytes) ----
// W:  [16 m][16 g][32 k] bf16, A-fragment order = 16384
// Mb: [16 pt][1024 k] bf16, XOR-swizzled (byte ^= ((m&7)^(g&7))<<4) = 32768
// F:  per-wave 2 buffers x 4KB: [4 cb][32 rho][16 ch] bf16, edge(rho)=((rho&3)<<3)|(rho>>2)
constexpr int W_OFF  = 0;
constexpr int MB_OFF = 16384;
constexpr int F_OFF  = 49152;
constexpr int LDS_BYTES = 81920;   // 2 blocks/CU at 160 KiB

typedef __attribute__((ext_vector_type(8))) short short8;
typedef __attribute__((ext_vector_type(4))) float f32x4;

static __device__ __forceinline__ u16 f2bf_rne(float f) {
  __hip_bfloat16 h = __float2bfloat16(f);
  return __builtin_bit_cast(u16, h);
}
static __device__ __forceinline__ u16 rbf(float f) {  // cheap round-half-up (2 VALU)
  u32 u = __builtin_bit_cast(u32, f);
  return (u16)((u + 0x8000u) >> 16);
}

// ---- prep 1: features f32 -> bf16 ----
__global__ void prep_feat(const float* __restrict__ in, u16* __restrict__ outb, int n2) {
  int i = blockIdx.x * blockDim.x + threadIdx.x;
  if (i < n2) {
    float2 v = ((const float2*)in)[i];
    u32 u = (u32)f2bf_rne(v.x) | ((u32)f2bf_rne(v.y) << 16);
    ((u32*)outb)[i] = u;
  }
}

// ---- prep 2: kernel f32 [g][i][o] -> bf16 in B-fragment order ----
__global__ void prep_k2f(const float* __restrict__ kern, u16* __restrict__ k2f) {
  int d = blockIdx.x * blockDim.x + threadIdx.x;   // 65536 total
  int e = d & 7, l = (d >> 3) & 63, ot = (d >> 9) & 3, ks = d >> 11;
  int k = ks * 32 + (l >> 4) * 8 + e;
  int o = ot * 16 + (l & 15);
  k2f[d] = f2bf_rne(kern[k * 64 + o]);
}

// async global->LDS: 16B per lane, per-lane global src (VGPR, laundered), imm offset 0
#define GLL0(g_, l_) __builtin_amdgcn_global_load_lds(                          \
    (const __attribute__((address_space(1))) unsigned int*)(const void*)(g_),   \
    (__attribute__((address_space(3))) unsigned int*)(void*)(l_), 16, 0, 0)

// issue one point's 4 staging loads (4 cb chunks, 1KB each) into buffer buf_.
// imm offset stays 0 (HW applies imm to BOTH global and LDS addr — r9 bug);
// chunk offsets live in laundered per-lane VGPR addresses + distinct LDS bases.
#define ISSUE(rv_, buf_) do {                                                   \
    __builtin_amdgcn_sched_barrier(0);                                          \
    const char* s_ = fb + (size_t)(u32)(rv_) * 128u + h16;                      \
    char* d_ = Fw + (buf_) * 4096;                                              \
    u64 sa0 = (u64)(s_ + 0);  asm("" : "+v"(sa0));                              \
    u64 sa1 = (u64)(s_ + 32); asm("" : "+v"(sa1));                              \
    u64 sa2 = (u64)(s_ + 64); asm("" : "+v"(sa2));                              \
    u64 sa3 = (u64)(s_ + 96); asm("" : "+v"(sa3));                              \
    GLL0(sa0, d_ + 0);                                                          \
    GLL0(sa1, d_ + 1024);                                                       \
    GLL0(sa2, d_ + 2048);                                                       \
    GLL0(sa3, d_ + 3072);                                                       \
  } while (0)

// build point t_ from staged buffer: conflict-free u16 reads -> pack -> 4 MFMA -> Mb
#define BUILDP(t_, buf_) do {                                                   \
    const int m_b = wid * 4 + (t_);                                             \
    const char* Fb = Fw + (buf_) * 4096;                                        \
    const short8 af = *(const short8*)(smem + W_OFF + m_b * 1024 + l15 * 64 + l4 * 16); \
    f32x4 accm[4];                                                              \
    _Pragma("unroll")                                                           \
    for (int ib = 0; ib < 4; ++ib) {                                            \
      u32 q[8];                                                                 \
      _Pragma("unroll")                                                         \
      for (int e = 0; e < 8; ++e)                                               \
        q[e] = (u32)*(const u16*)(Fb + ib * 1024 + (e * 4 + l4) * 32 + l15 * 2);\
      union { u32 u[4]; short8 s; } bb;                                         \
      _Pragma("unroll")                                                         \
      for (int j = 0; j < 4; ++j) bb.u[j] = q[2 * j] | (q[2 * j + 1] << 16);    \
      const f32x4 cz = {0.f, 0.f, 0.f, 0.f};                                    \
      accm[ib] = __builtin_amdgcn_mfma_f32_16x16x32_bf16(af, bb.s, cz, 0, 0, 0);\
    }                                                                           \
    _Pragma("unroll")                                                           \
    for (int ib = 0; ib < 4; ++ib)                                              \
      _Pragma("unroll")                                                         \
      for (int r = 0; r < 4; ++r) {                                             \
        const int g = l4 * 4 + r;                                               \
        const u32 k = (u32)(g * 64 + ib * 16 + l15);                            \
        u32 byt = (u32)m_b * 2048u + k * 2u;                                    \
        byt ^= ((u32)((m_b & 7) ^ (g & 7)) << 4);                               \
        *(u16*)(smem + MB_OFF + byt) = rbf(accm[ib][r]);                        \
      }                                                                         \
  } while (0)

// ---- main fused kernel: 16 points per block, 4 waves, 2 blocks/CU ----
__global__ __launch_bounds__(THREADS, 2) void cconv_main(
    const int* __restrict__ recv, const float* __restrict__ relpos,
    const float* __restrict__ wsup, const int* __restrict__ aptr,
    const u16* __restrict__ fbf, const u16* __restrict__ k2f,
    const float* __restrict__ bias, float* __restrict__ out) {
  extern __shared__ __align__(16) char smem[];
  const int tid = threadIdx.x;
  const int n0 = blockIdx.x * TM;
  const int wid = tid >> 6, lane = tid & 63;
  const int l15 = lane & 15, l4 = lane >> 4;

  char* Fw = smem + F_OFF + wid * 8192;
  const char* fb = (const char*)fbf;
  const int h16 = (lane & 1) * 16;

  // receiver ids for this lane's staged rows: LDS row rho = lane>>1 holds edge
  // e(rho) = ((rho&3)<<3)|(rho>>2)  (permutation cancels against MFMA k-slot map)
  const int rho = lane >> 1;
  const int e_l = ((rho & 3) << 3) | (rho >> 2);
  const int* rq = recv + (n0 + wid * 4) * PP + e_l;
  int rv0 = rq[0], rv1 = rq[PP], rv2 = rq[2 * PP], rv3 = rq[3 * PP];
  // pin: force materialization here so the loads can't sink into the build phase
  asm volatile("" : "+v"(rv0), "+v"(rv1), "+v"(rv2), "+v"(rv3));

  // stage points 0,1 now — latency hides under P0 + barrier
  ISSUE(rv0, 0);
  ISSUE(rv1, 1);

  // ---- P0: full W -> LDS in A-fragment order [m][g][k] ----
  {
    const float invws = 1.0f / wsup[0];
    int a = aptr[0];
    if (a < 0 || a > 64) a = (int)(*(const float*)aptr);  // dtype fallback
    #pragma unroll
    for (int ee = 0; ee < 2; ++ee) {
      const int e = tid + ee * 256;
      const int m = e >> 5, p = e & 31;
      const int ei = (n0 + m) * PP + p;
      const float2 rp2 = ((const float2*)relpos)[ei];
      const float rx = rp2.x * invws, ry = rp2.y * invws;
      const float d2 = rx * rx + ry * ry;
      const float w1 = fmaxf(1.0f - d2, 0.0f);
      float win = 1.0f;
      for (int q = 0; q < a; ++q) win *= w1;
      float gy = fminf(fmaxf((rx + 1.0f) * 1.5f, 0.0f), 3.0f);
      float gx = fminf(fmaxf((ry + 1.0f) * 1.5f, 0.0f), 3.0f);
      int y0 = (int)gy; y0 = y0 > 2 ? 2 : y0;
      int x0 = (int)gx; x0 = x0 > 2 ? 2 : x0;
      const float fy = gy - (float)y0, fx = gx - (float)x0;
      u16* wp = (u16*)(smem + W_OFF) + m * 512 + p;   // elem [m][g][k=p]
      #pragma unroll
      for (int g = 0; g < 16; ++g) {
        const int y = g >> 2, x = g & 3;
        const float wyv = (y == y0) ? (1.0f - fy) : (y == y0 + 1) ? fy : 0.0f;
        const float wxv = (x == x0) ? (1.0f - fx) : (x == x0 + 1) ? fx : 0.0f;
        wp[g * 32] = rbf(win * wyv * wxv);
      }
    }
  }
  __syncthreads();   // drains vmcnt(0): staged p0,p1 guaranteed landed

  // ---- build phase: 4 points per wave, double-buffered async staging ----
  BUILDP(0, 0);
  ISSUE(rv2, 0);     // safe: p0's reads consumed above
  BUILDP(1, 1);
  ISSUE(rv3, 1);
  asm volatile("s_waitcnt vmcnt(4)" ::: "memory");   // p2 landed (p3 still in flight)
  BUILDP(2, 0);
  asm volatile("s_waitcnt vmcnt(0)" ::: "memory");   // p3 landed
  BUILDP(3, 1);
  __syncthreads();

  // ---- single GEMM2: acc[16n x 16o per wave] = Mb[16n x 1024k] @ K2[1024k x 64o] ----
  f32x4 acc = {0.f, 0.f, 0.f, 0.f};
  {
    const u32 rowb = (u32)l15 * 2048u;
    const u32 swl = (u32)(l15 & 7) << 4;
    #pragma unroll 8
    for (int ks = 0; ks < 32; ++ks) {
      const u32 kc = (u32)ks * 32u + (u32)l4 * 8u;
      const u32 g7 = (((kc >> 6) & 7u) << 4);
      const u32 byt = (rowb + kc * 2u) ^ swl ^ g7;
      const short8 a2 = *(const short8*)(smem + MB_OFF + byt);
      const short8 b2 = *(const short8*)(k2f + ((u32)(ks * 4 + wid) * 64u + (u32)lane) * 8u);
      acc = __builtin_amdgcn_mfma_f32_16x16x32_bf16(a2, b2, acc, 0, 0, 0);
    }
  }

  // ---- epilogue: rows n = l4*4 + r (points), col o = wid*16 + l15 ----
  const int o = wid * 16 + l15;
  const float bv = bias[o];
  #pragma unroll
  for (int r = 0; r < 4; ++r)
    out[(n0 + l4 * 4 + r) * CH + o] = acc[r] * (1.0f / 32.0f) + bv;
}

extern "C" void kernel_launch(void* const* d_in, const int* in_sizes, int n_in,
                              void* d_out, int out_size, void* d_ws, size_t ws_size,
                              hipStream_t stream) {
  const float* features = (const float*)d_in[0];
  const int* receivers  = (const int*)d_in[1];
  const float* relpos   = (const float*)d_in[2];
  const float* wsup     = (const float*)d_in[3];
  const int* aptr       = (const int*)d_in[4];
  const float* kern     = (const float*)d_in[5];
  const float* bias     = (const float*)d_in[6];
  float* out = (float*)d_out;

  const int N = in_sizes[0] / CH;   // 50000
  u16* fbf = (u16*)d_ws;                                    // N*64 bf16 = 6.4 MB
  u16* k2f = (u16*)((char*)d_ws + (size_t)N * CH * 2);      // 128 KB, frag-ordered

  const int nfeat2 = in_sizes[0] / 2;
  prep_feat<<<dim3((nfeat2 + 255) / 256), dim3(256), 0, stream>>>(features, fbf, nfeat2);
  prep_k2f<<<dim3(65536 / 256), dim3(256), 0, stream>>>(kern, k2f);

  hipFuncSetAttribute((const void*)cconv_main,
                      hipFuncAttributeMaxDynamicSharedMemorySize, LDS_BYTES);
  cconv_main<<<dim3(N / TM), dim3(THREADS), LDS_BYTES, stream>>>(
      receivers, relpos, wsup, aptr, fbf, k2f, bias, out);
}

// Round 11
// 58.010 us; speedup vs baseline: 1.0803x; 1.0803x over previous
//
#include <hip/hip_runtime.h>
#include <hip/hip_bf16.h>

typedef unsigned short u16;
typedef unsigned int u32;

#define THREADS 256
constexpr int CH = 64;        // in/out channels
constexpr int PP = 32;        // neighbors per point
constexpr int TM = 16;        // points per block

// ---- LDS layout (bytes) ----
// Pb: [512 edges] x 16B params {fy,fx,win,y0|x0<<2}, slot = m*32 + (p ^ ((p>>3)&3)) = 8192
// Mb: [16 pt][1024 k] bf16, XOR-swizzled (byte ^= ((m&7)^(g&7))<<4) = 32768
constexpr int PB_OFF = 0;
constexpr int MB_OFF = 8192;
constexpr int LDS_BYTES = 40960;   // 4 blocks/CU at 160 KiB exactly

typedef __attribute__((ext_vector_type(8))) short short8;
typedef __attribute__((ext_vector_type(4))) float f32x4;

static __device__ __forceinline__ u16 f2bf_rne(float f) {
  __hip_bfloat16 h = __float2bfloat16(f);
  return __builtin_bit_cast(u16, h);
}
static __device__ __forceinline__ u16 rbf(float f) {  // cheap round-half-up (2 VALU)
  u32 u = __builtin_bit_cast(u32, f);
  return (u16)((u + 0x8000u) >> 16);
}

// ---- prep 1: features f32 -> bf16 ----
__global__ void prep_feat(const float* __restrict__ in, u16* __restrict__ outb, int n2) {
  int i = blockIdx.x * blockDim.x + threadIdx.x;
  if (i < n2) {
    float2 v = ((const float2*)in)[i];
    u32 u = (u32)f2bf_rne(v.x) | ((u32)f2bf_rne(v.y) << 16);
    ((u32*)outb)[i] = u;
  }
}

// ---- prep 2: kernel f32 [g][i][o] -> bf16 in B-fragment order ----
__global__ void prep_k2f(const float* __restrict__ kern, u16* __restrict__ k2f) {
  int d = blockIdx.x * blockDim.x + threadIdx.x;   // 65536 total
  int e = d & 7, l = (d >> 3) & 63, ot = (d >> 9) & 3, ks = d >> 11;
  int k = ks * 32 + (l >> 4) * 8 + e;
  int o = ot * 16 + (l & 15);
  k2f[d] = f2bf_rne(kern[k * 64 + o]);
}

// ---- main fused kernel: 16 points per block, 4 waves, 4 blocks/CU ----
__global__ __launch_bounds__(THREADS, 4) void cconv_main(
    const int* __restrict__ recv, const float* __restrict__ relpos,
    const float* __restrict__ wsup, const int* __restrict__ aptr,
    const u16* __restrict__ fbf, const u16* __restrict__ k2f,
    const float* __restrict__ bias, float* __restrict__ out) {
  __shared__ __align__(16) char smem[LDS_BYTES];
  const int tid = threadIdx.x;
  const int n0 = blockIdx.x * TM;
  const int wid = tid >> 6, lane = tid & 63;
  const int l15 = lane & 15, l4 = lane >> 4;
  const int gy_ = l15 >> 2, gx_ = l15 & 3;   // this lane's kernel bin g = l15

  // ---- P0: per-edge params into LDS (r2's proven idiom) ----
  {
    const float invws = 1.0f / wsup[0];
    int a = aptr[0];
    if (a < 0 || a > 64) a = (int)(*(const float*)aptr);  // dtype fallback
    #pragma unroll
    for (int ee = 0; ee < 2; ++ee) {
      const int e = tid + ee * 256;
      const int m = e >> 5, p = e & 31;
      const int ei = (n0 + m) * PP + p;
      const float2 rp2 = ((const float2*)relpos)[ei];
      const float rx = rp2.x * invws, ry = rp2.y * invws;
      const float d2 = rx * rx + ry * ry;
      const float w1 = fmaxf(1.0f - d2, 0.0f);
      float win = 1.0f;
      for (int q = 0; q < a; ++q) win *= w1;
      float gy = fminf(fmaxf((rx + 1.0f) * 1.5f, 0.0f), 3.0f);
      float gx = fminf(fmaxf((ry + 1.0f) * 1.5f, 0.0f), 3.0f);
      int y0 = (int)gy; y0 = y0 > 2 ? 2 : y0;
      int x0 = (int)gx; x0 = x0 > 2 ? 2 : x0;
      float4 pv;
      pv.x = gy - (float)y0;
      pv.y = gx - (float)x0;
      pv.z = win;
      pv.w = __builtin_bit_cast(float, (u32)(y0 | (x0 << 2)));
      const int slot = m * 32 + (p ^ ((p >> 3) & 3));   // bank-spread for frag reads
      *(float4*)(smem + PB_OFF + slot * 16) = pv;
    }
  }
  __syncthreads();

  // ---- build phase: each wave builds 4 points into Mb[16 pts] ----
  #pragma unroll
  for (int t = 0; t < 4; ++t) {
    const int m = wid * 4 + t;     // point 0..15, distinct per (wid,t)
    const int* rp = recv + (n0 + m) * PP + l4 * 8;
    const int4 A4 = *(const int4*)rp;
    const int4 B4 = *(const int4*)(rp + 4);
    // A fragment: W[g=l15][p=l4*8+e] reconstructed from params (broadcast reads)
    union { u16 h16[8]; short8 s; } au;
    #pragma unroll
    for (int e = 0; e < 8; ++e) {
      const int slot = m * 32 + l4 * 8 + (e ^ l4);
      const float4 pr = *(const float4*)(smem + PB_OFF + slot * 16);
      const u32 yx = __builtin_bit_cast(u32, pr.w);
      const int y0 = yx & 3, x0 = (yx >> 2) & 3;
      const float wyv = (gy_ == y0) ? (1.0f - pr.x) : ((gy_ == y0 + 1) ? pr.x : 0.0f);
      const float wxv = (gx_ == x0) ? (1.0f - pr.y) : ((gx_ == x0 + 1) ? pr.y : 0.0f);
      au.h16[e] = rbf(pr.z * wyv * wxv);
    }
    // B fragments: direct scalar gather (proven r7/r8 form)
    u32 vo[8];
    vo[0] = (u32)A4.x * 64u + (u32)l15; vo[1] = (u32)A4.y * 64u + (u32)l15;
    vo[2] = (u32)A4.z * 64u + (u32)l15; vo[3] = (u32)A4.w * 64u + (u32)l15;
    vo[4] = (u32)B4.x * 64u + (u32)l15; vo[5] = (u32)B4.y * 64u + (u32)l15;
    vo[6] = (u32)B4.z * 64u + (u32)l15; vo[7] = (u32)B4.w * 64u + (u32)l15;
    f32x4 accm[4];
    #pragma unroll
    for (int ib = 0; ib < 4; ++ib) {
      u32 q[8];
      #pragma unroll
      for (int e = 0; e < 8; ++e) q[e] = (u32)fbf[vo[e] + ib * 16];
      union { u32 u[4]; short8 s; } bb;
      #pragma unroll
      for (int j = 0; j < 4; ++j) bb.u[j] = q[2 * j] | (q[2 * j + 1] << 16);
      const f32x4 cz = {0.f, 0.f, 0.f, 0.f};
      accm[ib] = __builtin_amdgcn_mfma_f32_16x16x32_bf16(au.s, bb.s, cz, 0, 0, 0);
    }
    // stage M as bf16 into swizzled Mb: rows g = l4*4 + r, col i = ib*16 + l15
    #pragma unroll
    for (int ib = 0; ib < 4; ++ib)
      #pragma unroll
      for (int r = 0; r < 4; ++r) {
        const int g = l4 * 4 + r;
        const u32 k = (u32)(g * 64 + ib * 16 + l15);
        u32 byt = (u32)m * 2048u + k * 2u;
        byt ^= ((u32)((m & 7) ^ (g & 7)) << 4);
        *(u16*)(smem + MB_OFF + byt) = rbf(accm[ib][r]);
      }
  }
  __syncthreads();

  // ---- single GEMM2: acc[16n x 16o per wave] = Mb[16n x 1024k] @ K2[1024k x 64o] ----
  f32x4 acc = {0.f, 0.f, 0.f, 0.f};
  {
    const u32 rowb = (u32)l15 * 2048u;
    const u32 swl = (u32)(l15 & 7) << 4;
    #pragma unroll 8
    for (int ks = 0; ks < 32; ++ks) {
      const u32 kc = (u32)ks * 32u + (u32)l4 * 8u;
      const u32 g7 = (((kc >> 6) & 7u) << 4);
      const u32 byt = (rowb + kc * 2u) ^ swl ^ g7;
      const short8 a2 = *(const short8*)(smem + MB_OFF + byt);
      const short8 b2 = *(const short8*)(k2f + ((u32)(ks * 4 + wid) * 64u + (u32)lane) * 8u);
      acc = __builtin_amdgcn_mfma_f32_16x16x32_bf16(a2, b2, acc, 0, 0, 0);
    }
  }

  // ---- epilogue: rows n = l4*4 + r (points), col o = wid*16 + l15 ----
  const int o = wid * 16 + l15;
  const float bv = bias[o];
  #pragma unroll
  for (int r = 0; r < 4; ++r)
    out[(n0 + l4 * 4 + r) * CH + o] = acc[r] * (1.0f / 32.0f) + bv;
}

extern "C" void kernel_launch(void* const* d_in, const int* in_sizes, int n_in,
                              void* d_out, int out_size, void* d_ws, size_t ws_size,
                              hipStream_t stream) {
  const float* features = (const float*)d_in[0];
  const int* receivers  = (const int*)d_in[1];
  const float* relpos   = (const float*)d_in[2];
  const float* wsup     = (const float*)d_in[3];
  const int* aptr       = (const int*)d_in[4];
  const float* kern     = (const float*)d_in[5];
  const float* bias     = (const float*)d_in[6];
  float* out = (float*)d_out;

  const int N = in_sizes[0] / CH;   // 50000
  u16* fbf = (u16*)d_ws;                                    // N*64 bf16 = 6.4 MB
  u16* k2f = (u16*)((char*)d_ws + (size_t)N * CH * 2);      // 128 KB, frag-ordered

  const int nfeat2 = in_sizes[0] / 2;
  prep_feat<<<dim3((nfeat2 + 255) / 256), dim3(256), 0, stream>>>(features, fbf, nfeat2);
  prep_k2f<<<dim3(65536 / 256), dim3(256), 0, stream>>>(kern, k2f);

  cconv_main<<<dim3(N / TM), dim3(THREADS), 0, stream>>>(
      receivers, relpos, wsup, aptr, fbf, k2f, bias, out);
}

// Round 12
// 54.963 us; speedup vs baseline: 1.1402x; 1.0554x over previous
//
#include <hip/hip_runtime.h>
#include <hip/hip_bf16.h>

typedef unsigned short u16;
typedef unsigned int u32;

#define THREADS 512
constexpr int CH = 64;        // in/out channels
constexpr int PP = 32;        // neighbors per point
constexpr int TM = 16;        // points per block

// ---- LDS layout (bytes) ----
// W:  [16 m][16 g][32 p] bf16, A-fragment order = 16384   (dead after build)
// Rb: 4 KB f32 split-k partials, aliases W region
// Mb: [16 pt][1024 k] bf16, XOR-swizzled (byte ^= ((m&7)^(g&7))<<4) = 32768
constexpr int W_OFF  = 0;
constexpr int RB_OFF = 0;          // aliases W (W dead after build barrier)
constexpr int MB_OFF = 16384;
constexpr int LDS_BYTES = 49152;   // 3 blocks/CU at 160 KiB, 24 waves/CU

typedef __attribute__((ext_vector_type(8))) short short8;
typedef __attribute__((ext_vector_type(4))) float f32x4;

static __device__ __forceinline__ u16 f2bf_rne(float f) {
  __hip_bfloat16 h = __float2bfloat16(f);
  return __builtin_bit_cast(u16, h);
}
static __device__ __forceinline__ u16 rbf(float f) {  // cheap round-half-up (2 VALU)
  u32 u = __builtin_bit_cast(u32, f);
  return (u16)((u + 0x8000u) >> 16);
}

// ---- prep 1: features f32 -> bf16 ----
__global__ void prep_feat(const float* __restrict__ in, u16* __restrict__ outb, int n2) {
  int i = blockIdx.x * blockDim.x + threadIdx.x;
  if (i < n2) {
    float2 v = ((const float2*)in)[i];
    u32 u = (u32)f2bf_rne(v.x) | ((u32)f2bf_rne(v.y) << 16);
    ((u32*)outb)[i] = u;
  }
}

// ---- prep 2: kernel f32 [g][i][o] -> bf16 in B-fragment order ----
__global__ void prep_k2f(const float* __restrict__ kern, u16* __restrict__ k2f) {
  int d = blockIdx.x * blockDim.x + threadIdx.x;   // 65536 total
  int e = d & 7, l = (d >> 3) & 63, ot = (d >> 9) & 3, ks = d >> 11;
  int k = ks * 32 + (l >> 4) * 8 + e;
  int o = ot * 16 + (l & 15);
  k2f[d] = f2bf_rne(kern[k * 64 + o]);
}

// ---- main fused kernel: 16 points per block, 8 waves, 3 blocks/CU ----
__global__ __launch_bounds__(THREADS, 6) void cconv_main(
    const int* __restrict__ recv, const float* __restrict__ relpos,
    const float* __restrict__ wsup, const int* __restrict__ aptr,
    const u16* __restrict__ fbf, const u16* __restrict__ k2f,
    const float* __restrict__ bias, float* __restrict__ out) {
  __shared__ __align__(16) char smem[LDS_BYTES];
  const int tid = threadIdx.x;
  const int n0 = blockIdx.x * TM;
  const int wid = tid >> 6, lane = tid & 63;
  const int l15 = lane & 15, l4 = lane >> 4;
  const int pairp = wid & 3;    // o-tile (o = pairp*16 + l15)
  const int half  = wid >> 2;   // split-k half (ks = half*16 + j)

  // ---- P0: full W -> LDS in A-fragment order [m][g][p], 1 edge per thread ----
  {
    const float invws = 1.0f / wsup[0];
    int a = aptr[0];
    if (a < 0 || a > 64) a = (int)(*(const float*)aptr);  // dtype fallback
    const int e = tid;                 // 512 threads = 512 edges
    const int m = e >> 5, p = e & 31;
    const int ei = (n0 + m) * PP + p;
    const float2 rp2 = ((const float2*)relpos)[ei];
    const float rx = rp2.x * invws, ry = rp2.y * invws;
    const float d2 = rx * rx + ry * ry;
    const float w1 = fmaxf(1.0f - d2, 0.0f);
    float win = 1.0f;
    for (int q = 0; q < a; ++q) win *= w1;
    float gy = fminf(fmaxf((rx + 1.0f) * 1.5f, 0.0f), 3.0f);
    float gx = fminf(fmaxf((ry + 1.0f) * 1.5f, 0.0f), 3.0f);
    int y0 = (int)gy; y0 = y0 > 2 ? 2 : y0;
    int x0 = (int)gx; x0 = x0 > 2 ? 2 : x0;
    const float fy = gy - (float)y0, fx = gx - (float)x0;
    u16* wp = (u16*)(smem + W_OFF) + m * 512 + p;   // elem [m][g][p] = m*512 + g*32 + p
    #pragma unroll
    for (int g = 0; g < 16; ++g) {
      const int y = g >> 2, x = g & 3;
      const float wyv = (y == y0) ? (1.0f - fy) : (y == y0 + 1) ? fy : 0.0f;
      const float wxv = (x == x0) ? (1.0f - fx) : (x == x0 + 1) ? fx : 0.0f;
      wp[g * 32] = rbf(win * wyv * wxv);
    }
  }
  __syncthreads();

  // ---- build phase: each wave builds 2 points into Mb[16 pts] ----
  #pragma unroll
  for (int t = 0; t < 2; ++t) {
    const int m = wid * 2 + t;     // point 0..15, distinct per (wid,t)
    const int* rp = recv + (n0 + m) * PP + l4 * 8;
    const int4 A4 = *(const int4*)rp;
    const int4 B4 = *(const int4*)(rp + 4);
    const short8 af = *(const short8*)(smem + W_OFF + m * 1024 + l15 * 64 + l4 * 16);
    u32 vo[8];
    vo[0] = (u32)A4.x * 64u + (u32)l15; vo[1] = (u32)A4.y * 64u + (u32)l15;
    vo[2] = (u32)A4.z * 64u + (u32)l15; vo[3] = (u32)A4.w * 64u + (u32)l15;
    vo[4] = (u32)B4.x * 64u + (u32)l15; vo[5] = (u32)B4.y * 64u + (u32)l15;
    vo[6] = (u32)B4.z * 64u + (u32)l15; vo[7] = (u32)B4.w * 64u + (u32)l15;
    f32x4 accm[4];
    #pragma unroll
    for (int ib = 0; ib < 4; ++ib) {
      u32 q[8];
      #pragma unroll
      for (int e = 0; e < 8; ++e) q[e] = (u32)fbf[vo[e] + ib * 16];
      union { u32 u[4]; short8 s; } bb;
      #pragma unroll
      for (int j = 0; j < 4; ++j) bb.u[j] = q[2 * j] | (q[2 * j + 1] << 16);
      const f32x4 cz = {0.f, 0.f, 0.f, 0.f};
      accm[ib] = __builtin_amdgcn_mfma_f32_16x16x32_bf16(af, bb.s, cz, 0, 0, 0);
    }
    #pragma unroll
    for (int ib = 0; ib < 4; ++ib)
      #pragma unroll
      for (int r = 0; r < 4; ++r) {
        const int g = l4 * 4 + r;
        const u32 k = (u32)(g * 64 + ib * 16 + l15);
        u32 byt = (u32)m * 2048u + k * 2u;
        byt ^= ((u32)((m & 7) ^ (g & 7)) << 4);
        *(u16*)(smem + MB_OFF + byt) = rbf(accm[ib][r]);
      }
  }
  __syncthreads();

  // ---- split-k GEMM2: wave (pairp, half) computes partial over ks = half*16..+15 ----
  f32x4 acc = {0.f, 0.f, 0.f, 0.f};
  {
    const u32 rowb = (u32)l15 * 2048u;
    const u32 swl = (u32)(l15 & 7) << 4;
    #pragma unroll 8
    for (int j = 0; j < 16; ++j) {
      const int ks = half * 16 + j;
      const u32 kc = (u32)ks * 32u + (u32)l4 * 8u;
      const u32 g7 = (((kc >> 6) & 7u) << 4);
      const u32 byt = (rowb + kc * 2u) ^ swl ^ g7;
      const short8 a2 = *(const short8*)(smem + MB_OFF + byt);
      const short8 b2 = *(const short8*)(k2f + ((u32)(ks * 4 + pairp) * 64u + (u32)lane) * 8u);
      acc = __builtin_amdgcn_mfma_f32_16x16x32_bf16(a2, b2, acc, 0, 0, 0);
    }
  }

  // ---- split-k reduction through Rb (aliases dead W region) ----
  // slot for (row, col): pairp*1024 + row*64 + ((col ^ l4spread) ... XOR on col by l4
  if (half == 1) {
    #pragma unroll
    for (int r = 0; r < 4; ++r) {
      const int row = l4 * 4 + r;
      const u32 byt = (u32)pairp * 1024u + (u32)row * 64u + (u32)((l15 ^ l4) * 4);
      *(float*)(smem + RB_OFF + byt) = acc[r];
    }
  }
  __syncthreads();
  if (half == 0) {
    #pragma unroll
    for (int r = 0; r < 4; ++r) {
      const int row = l4 * 4 + r;
      const u32 byt = (u32)pairp * 1024u + (u32)row * 64u + (u32)((l15 ^ l4) * 4);
      acc[r] += *(const float*)(smem + RB_OFF + byt);
    }
    // ---- epilogue: rows n = l4*4 + r (points), col o = pairp*16 + l15 ----
    const int o = pairp * 16 + l15;
    const float bv = bias[o];
    #pragma unroll
    for (int r = 0; r < 4; ++r)
      out[(n0 + l4 * 4 + r) * CH + o] = acc[r] * (1.0f / 32.0f) + bv;
  }
}

extern "C" void kernel_launch(void* const* d_in, const int* in_sizes, int n_in,
                              void* d_out, int out_size, void* d_ws, size_t ws_size,
                              hipStream_t stream) {
  const float* features = (const float*)d_in[0];
  const int* receivers  = (const int*)d_in[1];
  const float* relpos   = (const float*)d_in[2];
  const float* wsup     = (const float*)d_in[3];
  const int* aptr       = (const int*)d_in[4];
  const float* kern     = (const float*)d_in[5];
  const float* bias     = (const float*)d_in[6];
  float* out = (float*)d_out;

  const int N = in_sizes[0] / CH;   // 50000
  u16* fbf = (u16*)d_ws;                                    // N*64 bf16 = 6.4 MB
  u16* k2f = (u16*)((char*)d_ws + (size_t)N * CH * 2);      // 128 KB, frag-ordered

  const int nfeat2 = in_sizes[0] / 2;
  prep_feat<<<dim3((nfeat2 + 255) / 256), dim3(256), 0, stream>>>(features, fbf, nfeat2);
  prep_k2f<<<dim3(65536 / 256), dim3(256), 0, stream>>>(kern, k2f);

  cconv_main<<<dim3(N / TM), dim3(THREADS), 0, stream>>>(
      receivers, relpos, wsup, aptr, fbf, k2f, bias, out);
}